// Round 11
// baseline (463.448 us; speedup 1.0000x reference)
//
#include <hip/hip_runtime.h>
#include <hip/hip_bf16.h>
#include <math.h>

#define NEG_SLOPE 0.2f

typedef __attribute__((ext_vector_type(8))) short bf16x8;
typedef __attribute__((ext_vector_type(4))) float f32x4;

__device__ __forceinline__ float lrelu(float x) { return x > 0.f ? x : NEG_SLOPE * x; }
__device__ __forceinline__ float blo(unsigned u) { return __uint_as_float(u << 16); }
__device__ __forceinline__ float bhi(unsigned u) { return __uint_as_float(u & 0xffff0000u); }
__device__ __forceinline__ unsigned short f2b(float f) {
    __hip_bfloat16 b = __float2bfloat16(f);
    return *(unsigned short*)&b;
}

// ---------- prep: convert x->bf16, W1->W1T bf16, W2->W2T bf16, deg histogram ----------
__global__ __launch_bounds__(256) void prep_kernel(
    const float* __restrict__ x, unsigned short* __restrict__ xb, long total8,
    const float* __restrict__ W1, unsigned short* __restrict__ W1T,
    const float* __restrict__ W2, unsigned short* __restrict__ W2T,
    const int* __restrict__ ei, int E, int EL, int* __restrict__ deg,
    int b_cx, int b_cw)
{
    const int b = blockIdx.x;
    if (b < b_cx) {
        long i = (long)b * 256 + threadIdx.x;
        if (i >= total8) return;
        const float4* src = (const float4*)x + 2 * i;
        float4 a = src[0], v = src[1];
        uint4 pk;
        pk.x = (unsigned)f2b(a.x) | ((unsigned)f2b(a.y) << 16);
        pk.y = (unsigned)f2b(a.z) | ((unsigned)f2b(a.w) << 16);
        pk.z = (unsigned)f2b(v.x) | ((unsigned)f2b(v.y) << 16);
        pk.w = (unsigned)f2b(v.z) | ((unsigned)f2b(v.w) << 16);
        ((uint4*)xb)[i] = pk;
    } else if (b < b_cx + b_cw) {
        int i = (b - b_cx) * 256 + threadIdx.x;
        if (i < 512 * 256) {
            int nn = i >> 8, k = i & 255;
            W1T[nn * 256 + k] = f2b(W1[k * 512 + nn]);
        } else if (i < 512 * 256 + 32 * 512) {
            int j = i - 512 * 256;
            int c = j >> 9, k = j & 511;
            W2T[c * 512 + k] = f2b(W2[k * 32 + c]);
        }
    } else {
        int e = (b - b_cx - b_cw) * 256 + threadIdx.x;
        if (e >= EL) return;
        int d = (e < E) ? ei[E + e] : e - E;
        atomicAdd(&deg[d], 1);
    }
}

// ---------- single-dispatch two-level scan (atomic handshake; all blocks co-resident) ----------
// ctrl[0]=publish counter, ctrl[1]=flag (both zeroed by the deg memset).
__global__ __launch_bounds__(256) void scan_fused_kernel(
    const int* __restrict__ deg, int* __restrict__ bsum, int* __restrict__ bsoff,
    int* __restrict__ rowptr, int* __restrict__ cursor, int* __restrict__ ctrl,
    int n, int EL, int nb)
{
    __shared__ int part[256];
    __shared__ int sbase;
    const int b = blockIdx.x, t = threadIdx.x;
    const int i = b * 256 + t;
    const int v = (i < n) ? deg[i] : 0;
    part[t] = v;
    __syncthreads();
    for (int off = 1; off < 256; off <<= 1) {
        int tmp = (t >= off) ? part[t - off] : 0;
        __syncthreads();
        part[t] += tmp;
        __syncthreads();
    }
    const int lexcl = part[t] - v;      // block-local exclusive prefix
    if (t == 255) bsum[b] = part[255];  // block total
    __threadfence();
    __syncthreads();
    if (t == 0) atomicAdd(&ctrl[0], 1);

    if (b == 0) {
        if (t == 0) {
            while (atomicAdd(&ctrl[0], 0) < nb) __builtin_amdgcn_s_sleep(1);
        }
        __syncthreads();
        int sv = (t < nb) ? atomicAdd(&bsum[t], 0) : 0;   // coherent read
        part[t] = sv;
        __syncthreads();
        for (int off = 1; off < 256; off <<= 1) {
            int tmp = (t >= off) ? part[t - off] : 0;
            __syncthreads();
            part[t] += tmp;
            __syncthreads();
        }
        if (t < nb) bsoff[t] = part[t] - sv;
        __threadfence();
        __syncthreads();
        if (t == 0) atomicExch(&ctrl[1], 1);
    }
    if (t == 0) {
        while (atomicAdd(&ctrl[1], 0) == 0) __builtin_amdgcn_s_sleep(1);
        sbase = atomicAdd(&bsoff[b], 0);                  // coherent read
    }
    __syncthreads();
    if (i < n) {
        int r = sbase + lexcl;
        rowptr[i] = r;
        cursor[i] = r;
    }
    if (i == n - 1) rowptr[n] = EL;
}

// ---------- merged GEMM1 + CSR-scatter: gemm1 tiles FIRST (long blocks), scatter backfills ----------
// GEMM1: 128x128 tile, BK=32, LDS rows padded 32->40, fused att1 dots (proven config).
__global__ __launch_bounds__(256) void gemm1_scatter_kernel(
    const int* __restrict__ ei, int E, int EL,
    int* __restrict__ cursor, int* __restrict__ csr_src,
    const unsigned short* __restrict__ xb, const unsigned short* __restrict__ W1T,
    unsigned short* __restrict__ xl1b,
    const float* __restrict__ att_src, const float* __restrict__ att_dst,
    float* __restrict__ a_src, float* __restrict__ a_dst,
    int M, int n_g)
{
    if (blockIdx.x >= n_g) {
        int e = (blockIdx.x - n_g) * 256 + threadIdx.x;
        if (e >= EL) return;
        int s, d;
        if (e < E) { s = ei[e]; d = ei[E + e]; } else { s = d = e - E; }
        int pos = atomicAdd(&cursor[d], 1);
        csr_src[pos] = s;
        return;
    }
    __shared__ unsigned short As[128 * 40];
    __shared__ unsigned short Bs[128 * 40];
    const int t    = blockIdx.x;
    const int row0 = (t >> 2) * 128;
    const int col0 = (t & 3) * 128;
    const int tid  = threadIdx.x;
    const int wave = tid >> 6;
    const int wrow = wave >> 1;
    const int wcol = wave & 1;
    const int lane = tid & 63;
    const int quad = lane >> 4;
    const int l15  = lane & 15;
    const int sm = tid >> 1;
    const int sk = (tid & 1) * 16;

    f32x4 acc[4][4] = {};

    for (int kb = 0; kb < 256; kb += 32) {
        uint4 a0 = make_uint4(0, 0, 0, 0), a1 = make_uint4(0, 0, 0, 0);
        if (row0 + sm < M) {
            const uint4* ap = (const uint4*)(xb + (size_t)(row0 + sm) * 256 + kb + sk);
            a0 = ap[0]; a1 = ap[1];
        }
        uint4* adp = (uint4*)&As[sm * 40 + sk];
        adp[0] = a0; adp[1] = a1;
        const uint4* bp = (const uint4*)(W1T + (size_t)(col0 + sm) * 256 + kb + sk);
        uint4* bd = (uint4*)&Bs[sm * 40 + sk];
        bd[0] = bp[0]; bd[1] = bp[1];
        __syncthreads();
        bf16x8 af[4], bf[4];
        #pragma unroll
        for (int mf = 0; mf < 4; ++mf)
            af[mf] = *(const bf16x8*)&As[(wrow * 64 + mf * 16 + l15) * 40 + quad * 8];
        #pragma unroll
        for (int nf = 0; nf < 4; ++nf)
            bf[nf] = *(const bf16x8*)&Bs[(wcol * 64 + nf * 16 + l15) * 40 + quad * 8];
        #pragma unroll
        for (int mf = 0; mf < 4; ++mf)
            #pragma unroll
            for (int nf = 0; nf < 4; ++nf)
                acc[mf][nf] = __builtin_amdgcn_mfma_f32_16x16x32_bf16(
                    af[mf], bf[nf], acc[mf][nf], 0, 0, 0);
        __syncthreads();
    }

    const int h = (t & 3) * 2 + wcol;
    float asv[4], adv[4];
    #pragma unroll
    for (int nf = 0; nf < 4; ++nf) {
        asv[nf] = att_src[h * 64 + nf * 16 + l15];
        adv[nf] = att_dst[h * 64 + nf * 16 + l15];
    }
    #pragma unroll
    for (int mf = 0; mf < 4; ++mf) {
        #pragma unroll
        for (int r = 0; r < 4; ++r) {
            const int row = row0 + wrow * 64 + mf * 16 + quad * 4 + r;
            float sv = 0.f, tv = 0.f;
            #pragma unroll
            for (int nf = 0; nf < 4; ++nf) {
                float v = acc[mf][nf][r];
                sv += v * asv[nf];
                tv += v * adv[nf];
            }
            sv += __shfl_xor(sv, 1); tv += __shfl_xor(tv, 1);
            sv += __shfl_xor(sv, 2); tv += __shfl_xor(tv, 2);
            sv += __shfl_xor(sv, 4); tv += __shfl_xor(tv, 4);
            sv += __shfl_xor(sv, 8); tv += __shfl_xor(tv, 8);
            if (row < M) {
                #pragma unroll
                for (int nf = 0; nf < 4; ++nf)
                    xl1b[(size_t)row * 512 + col0 + wcol * 64 + nf * 16 + l15] =
                        f2b(acc[mf][nf][r]);
                if (l15 == 0) { a_src[row * 8 + h] = sv; a_dst[row * 8 + h] = tv; }
            }
        }
    }
}

// ---------- fused layer-1 softmax + aggregate + bias + relu -> h1 (bf16) ----------
__global__ __launch_bounds__(256) void gather1_kernel(
    const int* __restrict__ rowptr, const int* __restrict__ csr_src,
    const unsigned short* __restrict__ xl1b, const float* __restrict__ a_src,
    const float* __restrict__ a_dst, const float* __restrict__ b1,
    unsigned short* __restrict__ h1, int M)
{
    int wid  = (blockIdx.x * blockDim.x + threadIdx.x) >> 6;
    int lane = threadIdx.x & 63;
    if (wid >= M) return;
    const int start = rowptr[wid], end = rowptr[wid + 1];
    const int h  = lane & 7;
    const int h0 = lane >> 3;
    const float adh = a_dst[wid * 8 + h];
    float dsum = 0.f;
    float acc0 = 0.f, acc1 = 0.f, acc2 = 0.f, acc3 = 0.f;
    float acc4 = 0.f, acc5 = 0.f, acc6 = 0.f, acc7 = 0.f;
    int   sN = csr_src[start];
    float aN = a_src[sN * 8 + h];
    uint4 vN = *(const uint4*)(xl1b + (size_t)sN * 512 + lane * 8);
    for (int j = start; j < end; ++j) {
        const float a = aN;
        const uint4 v = vN;
        const int jn = j + 1;
        if (jn < end) {
            int s2 = csr_src[jn];
            aN = a_src[s2 * 8 + h];
            vN = *(const uint4*)(xl1b + (size_t)s2 * 512 + lane * 8);
        }
        float p = __expf(lrelu(a + adh));
        dsum += p;
        float al = __shfl(p, h0);
        acc0 += blo(v.x) * al; acc1 += bhi(v.x) * al;
        acc2 += blo(v.y) * al; acc3 += bhi(v.y) * al;
        acc4 += blo(v.z) * al; acc5 += bhi(v.z) * al;
        acc6 += blo(v.w) * al; acc7 += bhi(v.w) * al;
    }
    const float ds  = __shfl(dsum, h0);
    const float inv = 1.f / (ds + 1e-16f);
    const float4 ba = *(const float4*)(b1 + lane * 8);
    const float4 bb = *(const float4*)(b1 + lane * 8 + 4);
    uint4 pk;
    pk.x = (unsigned)f2b(fmaxf(acc0 * inv + ba.x, 0.f)) | ((unsigned)f2b(fmaxf(acc1 * inv + ba.y, 0.f)) << 16);
    pk.y = (unsigned)f2b(fmaxf(acc2 * inv + ba.z, 0.f)) | ((unsigned)f2b(fmaxf(acc3 * inv + ba.w, 0.f)) << 16);
    pk.z = (unsigned)f2b(fmaxf(acc4 * inv + bb.x, 0.f)) | ((unsigned)f2b(fmaxf(acc5 * inv + bb.y, 0.f)) << 16);
    pk.w = (unsigned)f2b(fmaxf(acc6 * inv + bb.z, 0.f)) | ((unsigned)f2b(fmaxf(acc7 * inv + bb.w, 0.f)) << 16);
    ((uint4*)(h1 + (size_t)wid * 512))[lane] = pk;
}

// ---------- GEMM2 (MFMA bf16): xl2b[M,32](bf16) = h1[M,512] @ W2; fused att2 dots ----------
__global__ __launch_bounds__(256) void gemm2_mfma_kernel(
    const unsigned short* __restrict__ h1, const unsigned short* __restrict__ W2T,
    const float* __restrict__ att_src2, const float* __restrict__ att_dst2,
    unsigned short* __restrict__ xl2b, float* __restrict__ a_src2, float* __restrict__ a_dst2,
    int M)
{
    __shared__ unsigned short As[128 * 72];
    __shared__ unsigned short Bs[32 * 72];
    const int tid  = threadIdx.x;
    const int row0 = blockIdx.x * 128;
    const int wv   = tid >> 6;
    const int lane = tid & 63;
    const int quad = lane >> 4;
    const int l15  = lane & 15;

    f32x4 acc[2][2] = {};

    for (int kb = 0; kb < 512; kb += 64) {
        #pragma unroll
        for (int i = 0; i < 4; ++i) {
            int u = tid + 256 * i;
            int r = u >> 3;
            int kq = (u & 7) * 8;
            uint4 v = make_uint4(0, 0, 0, 0);
            if (row0 + r < M)
                v = *(const uint4*)(h1 + (size_t)(row0 + r) * 512 + kb + kq);
            *(uint4*)&As[r * 72 + kq] = v;
        }
        {
            int r = tid >> 3;
            int kq = (tid & 7) * 8;
            *(uint4*)&Bs[r * 72 + kq] = *(const uint4*)(W2T + (size_t)r * 512 + kb + kq);
        }
        __syncthreads();

        #pragma unroll
        for (int ks = 0; ks < 2; ++ks) {
            bf16x8 af[2], bf[2];
            #pragma unroll
            for (int mf = 0; mf < 2; ++mf)
                af[mf] = *(const bf16x8*)&As[(wv * 32 + mf * 16 + l15) * 72 + ks * 32 + quad * 8];
            #pragma unroll
            for (int nf = 0; nf < 2; ++nf)
                bf[nf] = *(const bf16x8*)&Bs[(nf * 16 + l15) * 72 + ks * 32 + quad * 8];
            #pragma unroll
            for (int mf = 0; mf < 2; ++mf)
                #pragma unroll
                for (int nf = 0; nf < 2; ++nf)
                    acc[mf][nf] = __builtin_amdgcn_mfma_f32_16x16x32_bf16(
                        af[mf], bf[nf], acc[mf][nf], 0, 0, 0);
        }
        __syncthreads();
    }

    float as2v[2], ad2v[2];
    #pragma unroll
    for (int nf = 0; nf < 2; ++nf) {
        as2v[nf] = att_src2[nf * 16 + l15];
        ad2v[nf] = att_dst2[nf * 16 + l15];
    }
    #pragma unroll
    for (int mf = 0; mf < 2; ++mf) {
        #pragma unroll
        for (int r = 0; r < 4; ++r) {
            const int row = row0 + wv * 32 + mf * 16 + quad * 4 + r;
            float v0 = acc[mf][0][r], v1 = acc[mf][1][r];
            float sv = v0 * as2v[0] + v1 * as2v[1];
            float tv = v0 * ad2v[0] + v1 * ad2v[1];
            sv += __shfl_xor(sv, 1); tv += __shfl_xor(tv, 1);
            sv += __shfl_xor(sv, 2); tv += __shfl_xor(tv, 2);
            sv += __shfl_xor(sv, 4); tv += __shfl_xor(tv, 4);
            sv += __shfl_xor(sv, 8); tv += __shfl_xor(tv, 8);
            if (row < M) {
                xl2b[(size_t)row * 32 + l15]      = f2b(v0);
                xl2b[(size_t)row * 32 + 16 + l15] = f2b(v1);
                if (l15 == 0) { a_src2[row] = sv; a_dst2[row] = tv; }
            }
        }
    }
}

// ---------- fused layer-2 softmax + aggregate + bias + relu + fc head (bf16 payload) ----------
// 4 edges in flight: lane = 16*g + c2; group g handles edges start+g (step 4);
// lane covers channel pair (2*c2, 2*c2+1) read as one packed uint (2 bf16).
__global__ __launch_bounds__(256) void gather2_head_kernel(
    const int* __restrict__ rowptr, const int* __restrict__ csr_src,
    const unsigned short* __restrict__ xl2b, const float* __restrict__ a_src2,
    const float* __restrict__ a_dst2, const float* __restrict__ b2,
    const float* __restrict__ fcW, const float* __restrict__ fcb,
    float* __restrict__ emb, float* __restrict__ logits, int M)
{
    __shared__ float sw[32][40];
    for (int i = threadIdx.x; i < 32 * 40; i += 256) sw[i / 40][i % 40] = fcW[i];
    __syncthreads();
    int wid  = (blockIdx.x * blockDim.x + threadIdx.x) >> 6;
    int lane = threadIdx.x & 63;
    if (wid >= M) return;
    const int start = rowptr[wid], end = rowptr[wid + 1];
    const float ad = a_dst2[wid];
    const int g  = lane >> 4;
    const int c2 = lane & 15;
    float dsum = 0.f;
    float accx = 0.f, accy = 0.f;
    for (int j = start + g; j < end; j += 4) {
        int s = csr_src[j];
        float p = __expf(lrelu(a_src2[s] + ad));
        dsum += p;
        unsigned u = *(const unsigned*)(xl2b + (size_t)s * 32 + 2 * c2);
        accx += p * blo(u);
        accy += p * bhi(u);
    }
    dsum += __shfl_xor(dsum, 16); accx += __shfl_xor(accx, 16); accy += __shfl_xor(accy, 16);
    dsum += __shfl_xor(dsum, 32); accx += __shfl_xor(accx, 32); accy += __shfl_xor(accy, 32);
    const float inv = 1.f / (dsum + 1e-16f);
    const float2 b2v = *(const float2*)(b2 + 2 * c2);
    float ex = fmaxf(accx * inv + b2v.x, 0.f);
    float ey = fmaxf(accy * inv + b2v.y, 0.f);
    if (g == 0) *(float2*)(emb + (size_t)wid * 32 + 2 * c2) = make_float2(ex, ey);
    const int col = (lane < 40) ? lane : 0;
    float lsum = (lane < 40) ? fcb[col] : 0.f;
    #pragma unroll
    for (int k = 0; k < 16; ++k) {
        float vx = __shfl(ex, k);
        float vy = __shfl(ey, k);
        lsum += vx * sw[2 * k][col] + vy * sw[2 * k + 1][col];
    }
    if (lane < 40) logits[(size_t)wid * 40 + lane] = lsum;
}

// ---------- launch ----------
extern "C" void kernel_launch(void* const* d_in, const int* in_sizes, int n_in,
                              void* d_out, int out_size, void* d_ws, size_t ws_size,
                              hipStream_t stream)
{
    const float* x   = (const float*)d_in[0];
    const int*   ei  = (const int*)d_in[1];
    const float* W1  = (const float*)d_in[2];
    const float* as1 = (const float*)d_in[3];
    const float* ad1 = (const float*)d_in[4];
    const float* b1  = (const float*)d_in[5];
    const float* W2  = (const float*)d_in[6];
    const float* as2 = (const float*)d_in[7];
    const float* ad2 = (const float*)d_in[8];
    const float* b2  = (const float*)d_in[9];
    const float* fcW = (const float*)d_in[10];
    const float* fcb = (const float*)d_in[11];

    const int n  = in_sizes[0] / 256;   // 50000
    const int e  = in_sizes[1] / 2;     // 800000
    const int el = e + n;               // with self-loops

    char* ws = (char*)d_ws;
    size_t off = 0;
    unsigned short* xb   = (unsigned short*)(ws + off); off += (size_t)n * 256 * 2;
    unsigned short* w1t  = (unsigned short*)(ws + off); off += (size_t)512 * 256 * 2;
    unsigned short* w2t  = (unsigned short*)(ws + off); off += (size_t)32 * 512 * 2;
    unsigned short* xl1b = (unsigned short*)(ws + off); off += (size_t)n * 512 * 2;
    unsigned short* h1   = (unsigned short*)(ws + off); off += (size_t)n * 512 * 2;
    float* a_src1 = (float*)(ws + off); off += (size_t)n * 8 * 4;
    float* a_dst1 = (float*)(ws + off); off += (size_t)n * 8 * 4;
    unsigned short* xl2b = (unsigned short*)(ws + off); off += (size_t)n * 32 * 2;
    float* a_src2 = (float*)(ws + off); off += (size_t)n * 4;
    float* a_dst2 = (float*)(ws + off); off += (size_t)n * 4;
    int*   deg    = (int*)(ws + off);   off += (size_t)n * 4;
    int*   ctrl   = (int*)(ws + off);   off += 2 * 4;     // contiguous with deg: one memset
    int*   rowptr = (int*)(ws + off);   off += (size_t)(n + 1) * 4;
    int*   cursor = (int*)(ws + off);   off += (size_t)n * 4;
    int*   csr_src= (int*)(ws + off);   off += (size_t)el * 4;
    int*   bsum   = (int*)(ws + off);   off += 256 * 4;
    int*   bsoff  = (int*)(ws + off);   off += 256 * 4;

    float* emb    = (float*)d_out;
    float* logits = (float*)d_out + (size_t)n * 32;

    // zero deg + ctrl in one memset (they are contiguous)
    hipMemsetAsync(deg, 0, ((size_t)n + 2) * 4, stream);

    const long total8 = (long)n * 256 / 8;
    const int b_cx = (int)((total8 + 255) / 256);
    const int b_cw = (512 * 256 + 32 * 512 + 255) / 256;
    const int b_dg = (el + 255) / 256;
    prep_kernel<<<b_cx + b_cw + b_dg, 256, 0, stream>>>(
        x, xb, total8, W1, w1t, W2, w2t, ei, e, el, deg, b_cx, b_cw);

    const int nb = (n + 255) / 256;     // 196 <= 256
    scan_fused_kernel<<<nb, 256, 0, stream>>>(
        deg, bsum, bsoff, rowptr, cursor, ctrl, n, el, nb);

    // merged GEMM1 (tiles first) + CSR scatter (backfills as tiles retire)
    const int n_tiles_y = (n + 127) / 128;
    const int n_g  = 4 * n_tiles_y;
    const int b_sc = (el + 255) / 256;
    gemm1_scatter_kernel<<<n_g + b_sc, 256, 0, stream>>>(
        ei, e, el, cursor, csr_src,
        xb, w1t, xl1b, as1, ad1, a_src1, a_dst1, n, n_g);

    gather1_kernel<<<((size_t)n * 64 + 255) / 256, 256, 0, stream>>>(
        rowptr, csr_src, xl1b, a_src1, a_dst1, b1, h1, n);
    gemm2_mfma_kernel<<<(n + 127) / 128, 256, 0, stream>>>(
        h1, w2t, as2, ad2, xl2b, a_src2, a_dst2, n);
    gather2_head_kernel<<<((size_t)n * 64 + 255) / 256, 256, 0, stream>>>(
        rowptr, csr_src, xl2b, a_src2, a_dst2, b2, fcW, fcb, emb, logits, n);
}

// Round 12
// 461.611 us; speedup vs baseline: 1.0040x; 1.0040x over previous
//
#include <hip/hip_runtime.h>
#include <hip/hip_bf16.h>
#include <math.h>

#define NEG_SLOPE 0.2f

typedef __attribute__((ext_vector_type(8))) short bf16x8;
typedef __attribute__((ext_vector_type(4))) float f32x4;

__device__ __forceinline__ float lrelu(float x) { return x > 0.f ? x : NEG_SLOPE * x; }
__device__ __forceinline__ float blo(unsigned u) { return __uint_as_float(u << 16); }
__device__ __forceinline__ float bhi(unsigned u) { return __uint_as_float(u & 0xffff0000u); }
__device__ __forceinline__ unsigned short f2b(float f) {
    __hip_bfloat16 b = __float2bfloat16(f);
    return *(unsigned short*)&b;
}

// ---------- prep: convert x->bf16, W1->W1T bf16, W2->W2T bf16, deg histogram ----------
__global__ __launch_bounds__(256) void prep_kernel(
    const float* __restrict__ x, unsigned short* __restrict__ xb, long total8,
    const float* __restrict__ W1, unsigned short* __restrict__ W1T,
    const float* __restrict__ W2, unsigned short* __restrict__ W2T,
    const int* __restrict__ ei, int E, int EL, int* __restrict__ deg,
    int b_cx, int b_cw)
{
    const int b = blockIdx.x;
    if (b < b_cx) {
        long i = (long)b * 256 + threadIdx.x;
        if (i >= total8) return;
        const float4* src = (const float4*)x + 2 * i;
        float4 a = src[0], v = src[1];
        uint4 pk;
        pk.x = (unsigned)f2b(a.x) | ((unsigned)f2b(a.y) << 16);
        pk.y = (unsigned)f2b(a.z) | ((unsigned)f2b(a.w) << 16);
        pk.z = (unsigned)f2b(v.x) | ((unsigned)f2b(v.y) << 16);
        pk.w = (unsigned)f2b(v.z) | ((unsigned)f2b(v.w) << 16);
        ((uint4*)xb)[i] = pk;
    } else if (b < b_cx + b_cw) {
        int i = (b - b_cx) * 256 + threadIdx.x;
        if (i < 512 * 256) {
            int nn = i >> 8, k = i & 255;
            W1T[nn * 256 + k] = f2b(W1[k * 512 + nn]);
        } else if (i < 512 * 256 + 32 * 512) {
            int j = i - 512 * 256;
            int c = j >> 9, k = j & 511;
            W2T[c * 512 + k] = f2b(W2[k * 32 + c]);
        }
    } else {
        int e = (b - b_cx - b_cw) * 256 + threadIdx.x;
        if (e >= EL) return;
        int d = (e < E) ? ei[E + e] : e - E;
        atomicAdd(&deg[d], 1);
    }
}

// ---------- single-dispatch two-level scan (atomic handshake; all blocks co-resident) ----------
__global__ __launch_bounds__(256) void scan_fused_kernel(
    const int* __restrict__ deg, int* __restrict__ bsum, int* __restrict__ bsoff,
    int* __restrict__ rowptr, int* __restrict__ cursor, int* __restrict__ ctrl,
    int n, int EL, int nb)
{
    __shared__ int part[256];
    __shared__ int sbase;
    const int b = blockIdx.x, t = threadIdx.x;
    const int i = b * 256 + t;
    const int v = (i < n) ? deg[i] : 0;
    part[t] = v;
    __syncthreads();
    for (int off = 1; off < 256; off <<= 1) {
        int tmp = (t >= off) ? part[t - off] : 0;
        __syncthreads();
        part[t] += tmp;
        __syncthreads();
    }
    const int lexcl = part[t] - v;
    if (t == 255) bsum[b] = part[255];
    __threadfence();
    __syncthreads();
    if (t == 0) atomicAdd(&ctrl[0], 1);

    if (b == 0) {
        if (t == 0) {
            while (atomicAdd(&ctrl[0], 0) < nb) __builtin_amdgcn_s_sleep(1);
        }
        __syncthreads();
        int sv = (t < nb) ? atomicAdd(&bsum[t], 0) : 0;
        part[t] = sv;
        __syncthreads();
        for (int off = 1; off < 256; off <<= 1) {
            int tmp = (t >= off) ? part[t - off] : 0;
            __syncthreads();
            part[t] += tmp;
            __syncthreads();
        }
        if (t < nb) bsoff[t] = part[t] - sv;
        __threadfence();
        __syncthreads();
        if (t == 0) atomicExch(&ctrl[1], 1);
    }
    if (t == 0) {
        while (atomicAdd(&ctrl[1], 0) == 0) __builtin_amdgcn_s_sleep(1);
        sbase = atomicAdd(&bsoff[b], 0);
    }
    __syncthreads();
    if (i < n) {
        int r = sbase + lexcl;
        rowptr[i] = r;
        cursor[i] = r;
    }
    if (i == n - 1) rowptr[n] = EL;
}

// ---------- merged GEMM1 + CSR-scatter (tiles first, scatter backfills) ----------
__global__ __launch_bounds__(256) void gemm1_scatter_kernel(
    const int* __restrict__ ei, int E, int EL,
    int* __restrict__ cursor, int* __restrict__ csr_src,
    const unsigned short* __restrict__ xb, const unsigned short* __restrict__ W1T,
    unsigned short* __restrict__ xl1b,
    const float* __restrict__ att_src, const float* __restrict__ att_dst,
    float* __restrict__ a_src, float* __restrict__ a_dst,
    int M, int n_g)
{
    if (blockIdx.x >= n_g) {
        int e = (blockIdx.x - n_g) * 256 + threadIdx.x;
        if (e >= EL) return;
        int s, d;
        if (e < E) { s = ei[e]; d = ei[E + e]; } else { s = d = e - E; }
        int pos = atomicAdd(&cursor[d], 1);
        csr_src[pos] = s;
        return;
    }
    __shared__ unsigned short As[128 * 40];
    __shared__ unsigned short Bs[128 * 40];
    const int t    = blockIdx.x;
    const int row0 = (t >> 2) * 128;
    const int col0 = (t & 3) * 128;
    const int tid  = threadIdx.x;
    const int wave = tid >> 6;
    const int wrow = wave >> 1;
    const int wcol = wave & 1;
    const int lane = tid & 63;
    const int quad = lane >> 4;
    const int l15  = lane & 15;
    const int sm = tid >> 1;
    const int sk = (tid & 1) * 16;

    f32x4 acc[4][4] = {};

    for (int kb = 0; kb < 256; kb += 32) {
        uint4 a0 = make_uint4(0, 0, 0, 0), a1 = make_uint4(0, 0, 0, 0);
        if (row0 + sm < M) {
            const uint4* ap = (const uint4*)(xb + (size_t)(row0 + sm) * 256 + kb + sk);
            a0 = ap[0]; a1 = ap[1];
        }
        uint4* adp = (uint4*)&As[sm * 40 + sk];
        adp[0] = a0; adp[1] = a1;
        const uint4* bp = (const uint4*)(W1T + (size_t)(col0 + sm) * 256 + kb + sk);
        uint4* bd = (uint4*)&Bs[sm * 40 + sk];
        bd[0] = bp[0]; bd[1] = bp[1];
        __syncthreads();
        bf16x8 af[4], bf[4];
        #pragma unroll
        for (int mf = 0; mf < 4; ++mf)
            af[mf] = *(const bf16x8*)&As[(wrow * 64 + mf * 16 + l15) * 40 + quad * 8];
        #pragma unroll
        for (int nf = 0; nf < 4; ++nf)
            bf[nf] = *(const bf16x8*)&Bs[(wcol * 64 + nf * 16 + l15) * 40 + quad * 8];
        #pragma unroll
        for (int mf = 0; mf < 4; ++mf)
            #pragma unroll
            for (int nf = 0; nf < 4; ++nf)
                acc[mf][nf] = __builtin_amdgcn_mfma_f32_16x16x32_bf16(
                    af[mf], bf[nf], acc[mf][nf], 0, 0, 0);
        __syncthreads();
    }

    const int h = (t & 3) * 2 + wcol;
    float asv[4], adv[4];
    #pragma unroll
    for (int nf = 0; nf < 4; ++nf) {
        asv[nf] = att_src[h * 64 + nf * 16 + l15];
        adv[nf] = att_dst[h * 64 + nf * 16 + l15];
    }
    #pragma unroll
    for (int mf = 0; mf < 4; ++mf) {
        #pragma unroll
        for (int r = 0; r < 4; ++r) {
            const int row = row0 + wrow * 64 + mf * 16 + quad * 4 + r;
            float sv = 0.f, tv = 0.f;
            #pragma unroll
            for (int nf = 0; nf < 4; ++nf) {
                float v = acc[mf][nf][r];
                sv += v * asv[nf];
                tv += v * adv[nf];
            }
            sv += __shfl_xor(sv, 1); tv += __shfl_xor(tv, 1);
            sv += __shfl_xor(sv, 2); tv += __shfl_xor(tv, 2);
            sv += __shfl_xor(sv, 4); tv += __shfl_xor(tv, 4);
            sv += __shfl_xor(sv, 8); tv += __shfl_xor(tv, 8);
            if (row < M) {
                #pragma unroll
                for (int nf = 0; nf < 4; ++nf)
                    xl1b[(size_t)row * 512 + col0 + wcol * 64 + nf * 16 + l15] =
                        f2b(acc[mf][nf][r]);
                if (l15 == 0) { a_src[row * 8 + h] = sv; a_dst[row * 8 + h] = tv; }
            }
        }
    }
}

// ---------- fused layer-1 softmax + aggregate + bias + relu -> h1 (bf16) ----------
// Width-4 edge batching: 4 independent csr/a_src/payload loads in flight per wave
// (MLP fix for HBM 46% / VALU 41% / both unsaturated).
__global__ __launch_bounds__(256) void gather1_kernel(
    const int* __restrict__ rowptr, const int* __restrict__ csr_src,
    const unsigned short* __restrict__ xl1b, const float* __restrict__ a_src,
    const float* __restrict__ a_dst, const float* __restrict__ b1,
    unsigned short* __restrict__ h1, int M)
{
    int wid  = (blockIdx.x * blockDim.x + threadIdx.x) >> 6;
    int lane = threadIdx.x & 63;
    if (wid >= M) return;
    const int start = rowptr[wid], end = rowptr[wid + 1];
    const int h  = lane & 7;
    const int h0 = lane >> 3;
    const float adh = a_dst[wid * 8 + h];
    float dsum = 0.f;
    float acc0 = 0.f, acc1 = 0.f, acc2 = 0.f, acc3 = 0.f;
    float acc4 = 0.f, acc5 = 0.f, acc6 = 0.f, acc7 = 0.f;
    int j = start;
    for (; j + 3 < end; j += 4) {
        const int s0 = csr_src[j + 0];
        const int s1 = csr_src[j + 1];
        const int s2 = csr_src[j + 2];
        const int s3 = csr_src[j + 3];
        const float a0 = a_src[s0 * 8 + h];
        const float a1 = a_src[s1 * 8 + h];
        const float a2 = a_src[s2 * 8 + h];
        const float a3 = a_src[s3 * 8 + h];
        const uint4 v0 = *(const uint4*)(xl1b + (size_t)s0 * 512 + lane * 8);
        const uint4 v1 = *(const uint4*)(xl1b + (size_t)s1 * 512 + lane * 8);
        const uint4 v2 = *(const uint4*)(xl1b + (size_t)s2 * 512 + lane * 8);
        const uint4 v3 = *(const uint4*)(xl1b + (size_t)s3 * 512 + lane * 8);
        const float p0 = __expf(lrelu(a0 + adh));
        const float p1 = __expf(lrelu(a1 + adh));
        const float p2 = __expf(lrelu(a2 + adh));
        const float p3 = __expf(lrelu(a3 + adh));
        dsum += (p0 + p1) + (p2 + p3);
        const float al0 = __shfl(p0, h0);
        const float al1 = __shfl(p1, h0);
        const float al2 = __shfl(p2, h0);
        const float al3 = __shfl(p3, h0);
        acc0 += blo(v0.x) * al0 + blo(v1.x) * al1 + blo(v2.x) * al2 + blo(v3.x) * al3;
        acc1 += bhi(v0.x) * al0 + bhi(v1.x) * al1 + bhi(v2.x) * al2 + bhi(v3.x) * al3;
        acc2 += blo(v0.y) * al0 + blo(v1.y) * al1 + blo(v2.y) * al2 + blo(v3.y) * al3;
        acc3 += bhi(v0.y) * al0 + bhi(v1.y) * al1 + bhi(v2.y) * al2 + bhi(v3.y) * al3;
        acc4 += blo(v0.z) * al0 + blo(v1.z) * al1 + blo(v2.z) * al2 + blo(v3.z) * al3;
        acc5 += bhi(v0.z) * al0 + bhi(v1.z) * al1 + bhi(v2.z) * al2 + bhi(v3.z) * al3;
        acc6 += blo(v0.w) * al0 + blo(v1.w) * al1 + blo(v2.w) * al2 + blo(v3.w) * al3;
        acc7 += bhi(v0.w) * al0 + bhi(v1.w) * al1 + bhi(v2.w) * al2 + bhi(v3.w) * al3;
    }
    for (; j < end; ++j) {
        const int s = csr_src[j];
        const float a = a_src[s * 8 + h];
        const uint4 v = *(const uint4*)(xl1b + (size_t)s * 512 + lane * 8);
        const float p = __expf(lrelu(a + adh));
        dsum += p;
        const float al = __shfl(p, h0);
        acc0 += blo(v.x) * al; acc1 += bhi(v.x) * al;
        acc2 += blo(v.y) * al; acc3 += bhi(v.y) * al;
        acc4 += blo(v.z) * al; acc5 += bhi(v.z) * al;
        acc6 += blo(v.w) * al; acc7 += bhi(v.w) * al;
    }
    const float ds  = __shfl(dsum, h0);
    const float inv = 1.f / (ds + 1e-16f);
    const float4 ba = *(const float4*)(b1 + lane * 8);
    const float4 bb = *(const float4*)(b1 + lane * 8 + 4);
    uint4 pk;
    pk.x = (unsigned)f2b(fmaxf(acc0 * inv + ba.x, 0.f)) | ((unsigned)f2b(fmaxf(acc1 * inv + ba.y, 0.f)) << 16);
    pk.y = (unsigned)f2b(fmaxf(acc2 * inv + ba.z, 0.f)) | ((unsigned)f2b(fmaxf(acc3 * inv + ba.w, 0.f)) << 16);
    pk.z = (unsigned)f2b(fmaxf(acc4 * inv + bb.x, 0.f)) | ((unsigned)f2b(fmaxf(acc5 * inv + bb.y, 0.f)) << 16);
    pk.w = (unsigned)f2b(fmaxf(acc6 * inv + bb.z, 0.f)) | ((unsigned)f2b(fmaxf(acc7 * inv + bb.w, 0.f)) << 16);
    ((uint4*)(h1 + (size_t)wid * 512))[lane] = pk;
}

// ---------- GEMM2 (MFMA bf16): xl2b[M,32](bf16) = h1[M,512] @ W2; fused att2 dots ----------
__global__ __launch_bounds__(256) void gemm2_mfma_kernel(
    const unsigned short* __restrict__ h1, const unsigned short* __restrict__ W2T,
    const float* __restrict__ att_src2, const float* __restrict__ att_dst2,
    unsigned short* __restrict__ xl2b, float* __restrict__ a_src2, float* __restrict__ a_dst2,
    int M)
{
    __shared__ unsigned short As[128 * 72];
    __shared__ unsigned short Bs[32 * 72];
    const int tid  = threadIdx.x;
    const int row0 = blockIdx.x * 128;
    const int wv   = tid >> 6;
    const int lane = tid & 63;
    const int quad = lane >> 4;
    const int l15  = lane & 15;

    f32x4 acc[2][2] = {};

    for (int kb = 0; kb < 512; kb += 64) {
        #pragma unroll
        for (int i = 0; i < 4; ++i) {
            int u = tid + 256 * i;
            int r = u >> 3;
            int kq = (u & 7) * 8;
            uint4 v = make_uint4(0, 0, 0, 0);
            if (row0 + r < M)
                v = *(const uint4*)(h1 + (size_t)(row0 + r) * 512 + kb + kq);
            *(uint4*)&As[r * 72 + kq] = v;
        }
        {
            int r = tid >> 3;
            int kq = (tid & 7) * 8;
            *(uint4*)&Bs[r * 72 + kq] = *(const uint4*)(W2T + (size_t)r * 512 + kb + kq);
        }
        __syncthreads();

        #pragma unroll
        for (int ks = 0; ks < 2; ++ks) {
            bf16x8 af[2], bf[2];
            #pragma unroll
            for (int mf = 0; mf < 2; ++mf)
                af[mf] = *(const bf16x8*)&As[(wv * 32 + mf * 16 + l15) * 72 + ks * 32 + quad * 8];
            #pragma unroll
            for (int nf = 0; nf < 2; ++nf)
                bf[nf] = *(const bf16x8*)&Bs[(nf * 16 + l15) * 72 + ks * 32 + quad * 8];
            #pragma unroll
            for (int mf = 0; mf < 2; ++mf)
                #pragma unroll
                for (int nf = 0; nf < 2; ++nf)
                    acc[mf][nf] = __builtin_amdgcn_mfma_f32_16x16x32_bf16(
                        af[mf], bf[nf], acc[mf][nf], 0, 0, 0);
        }
        __syncthreads();
    }

    float as2v[2], ad2v[2];
    #pragma unroll
    for (int nf = 0; nf < 2; ++nf) {
        as2v[nf] = att_src2[nf * 16 + l15];
        ad2v[nf] = att_dst2[nf * 16 + l15];
    }
    #pragma unroll
    for (int mf = 0; mf < 2; ++mf) {
        #pragma unroll
        for (int r = 0; r < 4; ++r) {
            const int row = row0 + wv * 32 + mf * 16 + quad * 4 + r;
            float v0 = acc[mf][0][r], v1 = acc[mf][1][r];
            float sv = v0 * as2v[0] + v1 * as2v[1];
            float tv = v0 * ad2v[0] + v1 * ad2v[1];
            sv += __shfl_xor(sv, 1); tv += __shfl_xor(tv, 1);
            sv += __shfl_xor(sv, 2); tv += __shfl_xor(tv, 2);
            sv += __shfl_xor(sv, 4); tv += __shfl_xor(tv, 4);
            sv += __shfl_xor(sv, 8); tv += __shfl_xor(tv, 8);
            if (row < M) {
                xl2b[(size_t)row * 32 + l15]      = f2b(v0);
                xl2b[(size_t)row * 32 + 16 + l15] = f2b(v1);
                if (l15 == 0) { a_src2[row] = sv; a_dst2[row] = tv; }
            }
        }
    }
}

// ---------- fused layer-2 softmax + aggregate + bias + relu + fc head (bf16 payload) ----------
__global__ __launch_bounds__(256) void gather2_head_kernel(
    const int* __restrict__ rowptr, const int* __restrict__ csr_src,
    const unsigned short* __restrict__ xl2b, const float* __restrict__ a_src2,
    const float* __restrict__ a_dst2, const float* __restrict__ b2,
    const float* __restrict__ fcW, const float* __restrict__ fcb,
    float* __restrict__ emb, float* __restrict__ logits, int M)
{
    __shared__ float sw[32][40];
    for (int i = threadIdx.x; i < 32 * 40; i += 256) sw[i / 40][i % 40] = fcW[i];
    __syncthreads();
    int wid  = (blockIdx.x * blockDim.x + threadIdx.x) >> 6;
    int lane = threadIdx.x & 63;
    if (wid >= M) return;
    const int start = rowptr[wid], end = rowptr[wid + 1];
    const float ad = a_dst2[wid];
    const int g  = lane >> 4;
    const int c2 = lane & 15;
    float dsum = 0.f;
    float accx = 0.f, accy = 0.f;
    for (int j = start + g; j < end; j += 4) {
        int s = csr_src[j];
        float p = __expf(lrelu(a_src2[s] + ad));
        dsum += p;
        unsigned u = *(const unsigned*)(xl2b + (size_t)s * 32 + 2 * c2);
        accx += p * blo(u);
        accy += p * bhi(u);
    }
    dsum += __shfl_xor(dsum, 16); accx += __shfl_xor(accx, 16); accy += __shfl_xor(accy, 16);
    dsum += __shfl_xor(dsum, 32); accx += __shfl_xor(accx, 32); accy += __shfl_xor(accy, 32);
    const float inv = 1.f / (dsum + 1e-16f);
    const float2 b2v = *(const float2*)(b2 + 2 * c2);
    float ex = fmaxf(accx * inv + b2v.x, 0.f);
    float ey = fmaxf(accy * inv + b2v.y, 0.f);
    if (g == 0) *(float2*)(emb + (size_t)wid * 32 + 2 * c2) = make_float2(ex, ey);
    const int col = (lane < 40) ? lane : 0;
    float lsum = (lane < 40) ? fcb[col] : 0.f;
    #pragma unroll
    for (int k = 0; k < 16; ++k) {
        float vx = __shfl(ex, k);
        float vy = __shfl(ey, k);
        lsum += vx * sw[2 * k][col] + vy * sw[2 * k + 1][col];
    }
    if (lane < 40) logits[(size_t)wid * 40 + lane] = lsum;
}

// ---------- launch ----------
extern "C" void kernel_launch(void* const* d_in, const int* in_sizes, int n_in,
                              void* d_out, int out_size, void* d_ws, size_t ws_size,
                              hipStream_t stream)
{
    const float* x   = (const float*)d_in[0];
    const int*   ei  = (const int*)d_in[1];
    const float* W1  = (const float*)d_in[2];
    const float* as1 = (const float*)d_in[3];
    const float* ad1 = (const float*)d_in[4];
    const float* b1  = (const float*)d_in[5];
    const float* W2  = (const float*)d_in[6];
    const float* as2 = (const float*)d_in[7];
    const float* ad2 = (const float*)d_in[8];
    const float* b2  = (const float*)d_in[9];
    const float* fcW = (const float*)d_in[10];
    const float* fcb = (const float*)d_in[11];

    const int n  = in_sizes[0] / 256;   // 50000
    const int e  = in_sizes[1] / 2;     // 800000
    const int el = e + n;               // with self-loops

    char* ws = (char*)d_ws;
    size_t off = 0;
    unsigned short* xb   = (unsigned short*)(ws + off); off += (size_t)n * 256 * 2;
    unsigned short* w1t  = (unsigned short*)(ws + off); off += (size_t)512 * 256 * 2;
    unsigned short* w2t  = (unsigned short*)(ws + off); off += (size_t)32 * 512 * 2;
    unsigned short* xl1b = (unsigned short*)(ws + off); off += (size_t)n * 512 * 2;
    unsigned short* h1   = (unsigned short*)(ws + off); off += (size_t)n * 512 * 2;
    float* a_src1 = (float*)(ws + off); off += (size_t)n * 8 * 4;
    float* a_dst1 = (float*)(ws + off); off += (size_t)n * 8 * 4;
    unsigned short* xl2b = (unsigned short*)(ws + off); off += (size_t)n * 32 * 2;
    float* a_src2 = (float*)(ws + off); off += (size_t)n * 4;
    float* a_dst2 = (float*)(ws + off); off += (size_t)n * 4;
    int*   deg    = (int*)(ws + off);   off += (size_t)n * 4;
    int*   ctrl   = (int*)(ws + off);   off += 2 * 4;
    int*   rowptr = (int*)(ws + off);   off += (size_t)(n + 1) * 4;
    int*   cursor = (int*)(ws + off);   off += (size_t)n * 4;
    int*   csr_src= (int*)(ws + off);   off += (size_t)el * 4;
    int*   bsum   = (int*)(ws + off);   off += 256 * 4;
    int*   bsoff  = (int*)(ws + off);   off += 256 * 4;

    float* emb    = (float*)d_out;
    float* logits = (float*)d_out + (size_t)n * 32;

    hipMemsetAsync(deg, 0, ((size_t)n + 2) * 4, stream);

    const long total8 = (long)n * 256 / 8;
    const int b_cx = (int)((total8 + 255) / 256);
    const int b_cw = (512 * 256 + 32 * 512 + 255) / 256;
    const int b_dg = (el + 255) / 256;
    prep_kernel<<<b_cx + b_cw + b_dg, 256, 0, stream>>>(
        x, xb, total8, W1, w1t, W2, w2t, ei, e, el, deg, b_cx, b_cw);

    const int nb = (n + 255) / 256;
    scan_fused_kernel<<<nb, 256, 0, stream>>>(
        deg, bsum, bsoff, rowptr, cursor, ctrl, n, el, nb);

    const int n_tiles_y = (n + 127) / 128;
    const int n_g  = 4 * n_tiles_y;
    const int b_sc = (el + 255) / 256;
    gemm1_scatter_kernel<<<n_g + b_sc, 256, 0, stream>>>(
        ei, e, el, cursor, csr_src,
        xb, w1t, xl1b, as1, ad1, a_src1, a_dst1, n, n_g);

    gather1_kernel<<<((size_t)n * 64 + 255) / 256, 256, 0, stream>>>(
        rowptr, csr_src, xl1b, a_src1, a_dst1, b1, h1, n);
    gemm2_mfma_kernel<<<(n + 127) / 128, 256, 0, stream>>>(
        h1, w2t, as2, ad2, xl2b, a_src2, a_dst2, n);
    gather2_head_kernel<<<((size_t)n * 64 + 255) / 256, 256, 0, stream>>>(
        rowptr, csr_src, xl2b, a_src2, a_dst2, b2, fcW, fcb, emb, logits, n);
}